// Round 20
// baseline (106.345 us; speedup 1.0000x reference)
//
#include <hip/hip_runtime.h>
#include <hip/hip_bf16.h>
#include <cstdint>
#include <cstddef>
#include <cmath>

typedef __attribute__((ext_vector_type(8))) short short8v;
typedef __attribute__((ext_vector_type(4))) float f32x4;
typedef __attribute__((ext_vector_type(4))) unsigned short ushort4v;

__device__ __forceinline__ unsigned short f2bf(float f) {
  union { float f; uint32_t u; } v; v.f = f;
  uint32_t u = v.u;
  return (unsigned short)((u + 0x7fffu + ((u >> 16) & 1u)) >> 16);
}

__device__ __forceinline__ float bf2f(unsigned short u) {
  union { uint32_t u; float f; } v; v.u = ((uint32_t)u) << 16; return v.f;
}

__device__ __forceinline__ uint32_t pack2bf(float a, float b) {
  __hip_bfloat162 h = __float22bfloat162_rn(make_float2(a, b));
  union { __hip_bfloat162 h; uint32_t u; } c; c.h = h; return c.u;
}

__device__ __forceinline__ void load_lds_16B(const void* g, void* l) {
  __builtin_amdgcn_global_load_lds((const __attribute__((address_space(1))) void*)g,
                                   (__attribute__((address_space(3))) void*)l, 16, 0, 0);
}

// ---------------- fused prep: cvt x -> bf16  +  transpose Wa, Wp ----------------
__global__ __launch_bounds__(256) void prep_kernel(const float* __restrict__ x,
                                                   unsigned short* __restrict__ xb,
                                                   const float* __restrict__ Wa,
                                                   unsigned short* __restrict__ WaT,
                                                   const float* __restrict__ Wp,
                                                   unsigned short* __restrict__ WpT) {
  __shared__ float tile[64][65];
  int bid = blockIdx.x;
  int tid = threadIdx.x;

  if (bid < 2048) {
    int i = bid * 256 + tid;
    const float4* s4 = (const float4*)x + (size_t)i * 2;
    float4 f0 = s4[0], f1 = s4[1];
    short8v o;
    o[0] = (short)f2bf(f0.x); o[1] = (short)f2bf(f0.y);
    o[2] = (short)f2bf(f0.z); o[3] = (short)f2bf(f0.w);
    o[4] = (short)f2bf(f1.x); o[5] = (short)f2bf(f1.y);
    o[6] = (short)f2bf(f1.z); o[7] = (short)f2bf(f1.w);
    *(short8v*)(xb + (size_t)i * 8) = o;
    return;
  }

  int t = bid - 2048;
  const float* W; unsigned short* WT; int N, n0, k0;
  if (t < 768) { W = Wa; WT = WaT; N = 3072; n0 = (t % 48) * 64; k0 = (t / 48) * 64; }
  else { t -= 768; W = Wp; WT = WpT; N = 1024; n0 = (t % 16) * 64; k0 = (t / 16) * 64; }
  const int K = 1024;

#pragma unroll
  for (int i = 0; i < 4; ++i) {
    int idx = i * 256 + tid;
    int r = idx >> 4, c4 = (idx & 15) * 4;
    float4 v = *(const float4*)(W + (size_t)(k0 + r) * N + n0 + c4);
    tile[r][c4] = v.x; tile[r][c4 + 1] = v.y; tile[r][c4 + 2] = v.z; tile[r][c4 + 3] = v.w;
  }
  __syncthreads();
#pragma unroll
  for (int i = 0; i < 4; ++i) {
    int idx = i * 256 + tid;
    int nr = idx >> 4, k4 = (idx & 15) * 4;
    ushort4 o;
    o.x = f2bf(tile[k4 + 0][nr]);
    o.y = f2bf(tile[k4 + 1][nr]);
    o.z = f2bf(tile[k4 + 2][nr]);
    o.w = f2bf(tile[k4 + 3][nr]);
    *(ushort4*)(WT + (size_t)(n0 + nr) * K + k0 + k4) = o;
  }
}

// ---------------- GEMM1: qkv projection, 64x128 tiles (6 blocks/CU), fused V transpose ----
__global__ __launch_bounds__(256) void gemm_qkv_kernel(const unsigned short* __restrict__ A,
                                                       const unsigned short* __restrict__ BT,
                                                       unsigned short* __restrict__ qk,
                                                       unsigned short* __restrict__ VT) {
  const int K = 1024, N = 3072;
  __shared__ __align__(16) char lds[24576];
  char* As = lds;            // [64 m][64 k], slot^=(row&7)  (8 KB)
  char* Bs = lds + 8192;     // [128 n][64 k], slot^=(row&7) (16 KB)

  int nbn = N >> 7;          // 24
  int nwg = gridDim.x;       // 1536
  int wg = blockIdx.x;
  int per = nwg >> 3;
  int swz = (wg & 7) * per + (wg >> 3);
  int tm = swz / nbn, tn = swz % nbn;

  int tid = threadIdx.x;
  int wid = tid >> 6, lane = tid & 63;
  int l15 = lane & 15, lhi = lane >> 4;

  const unsigned short* Abase = A + (size_t)(tm * 64) * K;
  const unsigned short* Bbase = BT + (size_t)(tn * 128) * K;

  size_t ofsA[2], ofsB[4];
#pragma unroll
  for (int i = 0; i < 2; ++i) {
    int row = i * 32 + (tid >> 3);
    int ss = (tid & 7) ^ (row & 7);
    ofsA[i] = (size_t)row * K + ss * 8;
  }
#pragma unroll
  for (int i = 0; i < 4; ++i) {
    int row = i * 32 + (tid >> 3);
    int ss = (tid & 7) ^ (row & 7);
    ofsB[i] = (size_t)row * K + ss * 8;
  }

  f32x4 acc[4][2] = {};

  for (int kt = 0; kt < K; kt += 64) {
    __syncthreads();
#pragma unroll
    for (int i = 0; i < 2; ++i)
      load_lds_16B(Abase + ofsA[i] + kt, As + i * 4096 + tid * 16);
#pragma unroll
    for (int i = 0; i < 4; ++i)
      load_lds_16B(Bbase + ofsB[i] + kt, Bs + i * 4096 + tid * 16);
    __syncthreads();

#pragma unroll
    for (int ks = 0; ks < 2; ++ks) {
      short8v af[4], bfr[2];
#pragma unroll
      for (int mi = 0; mi < 4; ++mi) {
        int row = mi * 16 + l15;
        int ss = (ks * 4 + lhi) ^ (row & 7);
        af[mi] = *(const short8v*)(As + row * 128 + ss * 16);
      }
#pragma unroll
      for (int ni = 0; ni < 2; ++ni) {
        int row = wid * 32 + ni * 16 + l15;
        int ss = (ks * 4 + lhi) ^ (row & 7);
        bfr[ni] = *(const short8v*)(Bs + row * 128 + ss * 16);
      }
#pragma unroll
      for (int mi = 0; mi < 4; ++mi)
#pragma unroll
        for (int ni = 0; ni < 2; ++ni)
          acc[mi][ni] = __builtin_amdgcn_mfma_f32_16x16x32_bf16(af[mi], bfr[ni], acc[mi][ni], 0, 0, 0);
    }
  }

#pragma unroll
  for (int mi = 0; mi < 4; ++mi)
#pragma unroll
    for (int ni = 0; ni < 2; ++ni) {
      int col = tn * 128 + wid * 32 + ni * 16 + l15;
      int row0 = tm * 64 + mi * 16 + lhi * 4;
      if (col < 2048) {
#pragma unroll
        for (int r = 0; r < 4; ++r)
          qk[(size_t)(row0 + r) * 2048 + col] = f2bf(acc[mi][ni][r]);
      } else {
        int hl = col - 2048, hh = hl >> 6, d = hl & 63;
        int bb = row0 >> 11, tl = row0 & 2047;
        int tc = tl >> 6, k = (tl & 63) >> 2;
        int c4 = ((k >> 3) << 5) | ((k & 3) << 3) | (k & 4);
        ushort4 w;
        w.x = f2bf(acc[mi][ni][0]); w.y = f2bf(acc[mi][ni][1]);
        w.z = f2bf(acc[mi][ni][2]); w.w = f2bf(acc[mi][ni][3]);
        *(ushort4*)(VT + ((size_t)((bb * 16 + hh) * 64 + d)) * 2048 + tc * 64 + c4) = w;
      }
    }
}

// ---------------- GEMM2: 64x64 tiles (f32 out), grid 1024 = 4 blocks/CU ----------------
__global__ __launch_bounds__(256) void gemm_bt64x64_kernel(const unsigned short* __restrict__ A,
                                                           const unsigned short* __restrict__ BT,
                                                           float* __restrict__ Cout,
                                                           int M, int N, int K) {
  __shared__ __align__(16) char lds[16384];
  char* As = lds;
  char* Bs = lds + 8192;

  int nbn = N >> 6;
  int nwg = gridDim.x;
  int wg = blockIdx.x;
  int per = nwg >> 3;
  int swz = (wg & 7) * per + (wg >> 3);
  int tm = swz / nbn, tn = swz % nbn;

  int tid = threadIdx.x;
  int wid = tid >> 6, lane = tid & 63;
  int l15 = lane & 15, lhi = lane >> 4;
  int wm = wid >> 1, wn = wid & 1;

  const unsigned short* Abase = A + (size_t)(tm * 64) * K;
  const unsigned short* Bbase = BT + (size_t)(tn * 64) * K;

  size_t ofs2[2];
#pragma unroll
  for (int i = 0; i < 2; ++i) {
    int row = i * 32 + (tid >> 3);
    int ss = (tid & 7) ^ (row & 7);
    ofs2[i] = (size_t)row * K + ss * 8;
  }

  f32x4 acc[2][2] = {};

  for (int kt = 0; kt < K; kt += 64) {
    __syncthreads();
#pragma unroll
    for (int i = 0; i < 2; ++i)
      load_lds_16B(Abase + ofs2[i] + kt, As + i * 4096 + tid * 16);
#pragma unroll
    for (int i = 0; i < 2; ++i)
      load_lds_16B(Bbase + ofs2[i] + kt, Bs + i * 4096 + tid * 16);
    __syncthreads();

#pragma unroll
    for (int ks = 0; ks < 2; ++ks) {
      short8v af[2], bfr[2];
#pragma unroll
      for (int mi = 0; mi < 2; ++mi) {
        int row = wm * 32 + mi * 16 + l15;
        int ss = (ks * 4 + lhi) ^ (row & 7);
        af[mi] = *(const short8v*)(As + row * 128 + ss * 16);
      }
#pragma unroll
      for (int ni = 0; ni < 2; ++ni) {
        int row = wn * 32 + ni * 16 + l15;
        int ss = (ks * 4 + lhi) ^ (row & 7);
        bfr[ni] = *(const short8v*)(Bs + row * 128 + ss * 16);
      }
#pragma unroll
      for (int mi = 0; mi < 2; ++mi)
#pragma unroll
        for (int ni = 0; ni < 2; ++ni)
          acc[mi][ni] = __builtin_amdgcn_mfma_f32_16x16x32_bf16(af[mi], bfr[ni], acc[mi][ni], 0, 0, 0);
    }
  }

#pragma unroll
  for (int mi = 0; mi < 2; ++mi)
#pragma unroll
    for (int ni = 0; ni < 2; ++ni)
#pragma unroll
      for (int r = 0; r < 4; ++r) {
        int row = tm * 64 + wm * 32 + mi * 16 + lhi * 4 + r;
        int col = tn * 64 + wn * 32 + ni * 16 + l15;
        Cout[(size_t)row * N + col] = acc[mi][ni][r];
      }
}

// ---------------- causal flash attention (r17 version, proven 43 us) ----------------
__device__ __forceinline__ short8v scale_q(short8v q) {
  short8v r;
#pragma unroll
  for (int j = 0; j < 8; ++j)
    r[j] = (short)f2bf(bf2f((unsigned short)q[j]) * 0.18033688f);  // 0.125*log2(e)
  return r;
}

__device__ __forceinline__ void mask_diag(f32x4 s[4], int q_abs, int k0, int lhi) {
#pragma unroll
  for (int ni = 0; ni < 4; ++ni)
#pragma unroll
    for (int r = 0; r < 4; ++r) {
      int kv = k0 + ni * 16 + lhi * 4 + r;
      if (kv > q_abs) s[ni][r] = -1e30f;
    }
}

__device__ __forceinline__ void exp_p(f32x4 s[4]) {
#pragma unroll
  for (int ni = 0; ni < 4; ++ni)
#pragma unroll
    for (int r = 0; r < 4; ++r)
      s[ni][r] = exp2f(s[ni][r]);
}

// pa[ks] elems (jj = t*4+u): P[q=l15][kv = ks*32 + t*16 + lhi*4 + u] = s[ks*2+t][u]
__device__ __forceinline__ void repack_pa(const f32x4 s[4], short8v pa[2]) {
#pragma unroll
  for (int ks = 0; ks < 2; ++ks) {
    union { uint32_t u[4]; short8v v; } pk;
    pk.u[0] = pack2bf(s[2 * ks][0], s[2 * ks][1]);
    pk.u[1] = pack2bf(s[2 * ks][2], s[2 * ks][3]);
    pk.u[2] = pack2bf(s[2 * ks + 1][0], s[2 * ks + 1][1]);
    pk.u[3] = pack2bf(s[2 * ks + 1][2], s[2 * ks + 1][3]);
    pa[ks] = pk.v;
  }
}

__global__ __launch_bounds__(256) void attn_kernel(const unsigned short* __restrict__ qk,
                                                   const unsigned short* __restrict__ VT,
                                                   unsigned short* __restrict__ yb) {
  const int T = 2048, LD = 2048;
  int bid = blockIdx.x;                 // 1024 blocks
  int qt = 31 - (bid >> 5);             // LPT: biggest tiles dispatch first
  int bh = bid & 31;                    // bid%8 == bh%8 -> per-head XCD affinity
  int b = bh >> 4, h = bh & 15;

  int tid = threadIdx.x;
  int wid = tid >> 6, lane = tid & 63;
  int l15 = lane & 15, lhi = lane >> 4;

  __shared__ __align__(16) char Ks[2][8192];   // [64 kv][64 d] bf16, slot^=(kv&7)
  __shared__ __align__(16) char Vt[2][8192];   // [64 d][64 c] bf16, slot^=(d&7)

  union { uint32_t u[4]; short8v v; } ob;
  ob.u[0] = ob.u[1] = ob.u[2] = ob.u[3] = 0x3F803F80u;
  const short8v onesv = ob.v;

  int qrow = qt * 64 + wid * 16 + l15;
  const unsigned short* qp = qk + (size_t)(b * T + qrow) * LD + h * 64;
  short8v qf[2];
  qf[0] = scale_q(*(const short8v*)(qp + lhi * 8));
  qf[1] = scale_q(*(const short8v*)(qp + 32 + lhi * 8));

  const unsigned short* kbase = qk + (size_t)b * T * LD + 1024 + h * 64;
  const unsigned short* vtbase = VT + (size_t)(b * 16 + h) * 64 * 2048;

  f32x4 o[4] = {};
  f32x4 lf = {};
  int q_abs = qrow;
  int nt = qt + 1;

  auto stageK = [&](int s) {
#pragma unroll
    for (int i2 = 0; i2 < 2; ++i2) {
      int row = i2 * 32 + (tid >> 3);
      int ss = (tid & 7) ^ (row & 7);
      load_lds_16B(kbase + (size_t)(s * 64 + row) * LD + ss * 8, Ks[s & 1] + i2 * 4096 + tid * 16);
    }
  };
  auto stageV = [&](int s) {
#pragma unroll
    for (int i2 = 0; i2 < 2; ++i2) {
      int row = i2 * 32 + (tid >> 3);
      int ss = (tid & 7) ^ (row & 7);
      load_lds_16B(vtbase + (size_t)row * 2048 + s * 64 + ss * 8, Vt[s & 1] + i2 * 4096 + tid * 16);
    }
  };

  stageK(0); stageV(0);
  __syncthreads();

  for (int s = 0; s < nt; ++s) {
    if (s + 1 < nt) { stageK(s + 1); stageV(s + 1); }

    const char* KC = Ks[s & 1];
    const char* VC = Vt[s & 1];
    int k0 = s * 64;

    f32x4 sv[4] = {};
    __builtin_amdgcn_s_setprio(1);
#pragma unroll
    for (int ks = 0; ks < 2; ++ks)
#pragma unroll
      for (int ni = 0; ni < 4; ++ni) {
        int row = ni * 16 + l15;
        int sl = (ks * 4 + lhi) ^ (row & 7);
        short8v kf = *(const short8v*)(KC + row * 128 + sl * 16);
        sv[ni] = __builtin_amdgcn_mfma_f32_16x16x32_bf16(kf, qf[ks], sv[ni], 0, 0, 0);
      }
    __builtin_amdgcn_s_setprio(0);

    if (s == qt) mask_diag(sv, q_abs, k0, lhi);
    exp_p(sv);

    short8v pa[2];
    repack_pa(sv, pa);

    __builtin_amdgcn_s_setprio(1);
#pragma unroll
    for (int ks = 0; ks < 2; ++ks) {
#pragma unroll
      for (int nd = 0; nd < 4; ++nd) {
        int d = nd * 16 + l15;
        int slv = (ks * 4 + lhi) ^ (d & 7);
        short8v bv = *(const short8v*)(VC + d * 128 + slv * 16);
        o[nd] = __builtin_amdgcn_mfma_f32_16x16x32_bf16(pa[ks], bv, o[nd], 0, 0, 0);
      }
      lf = __builtin_amdgcn_mfma_f32_16x16x32_bf16(pa[ks], onesv, lf, 0, 0, 0);
    }
    __builtin_amdgcn_s_setprio(0);

    __syncthreads();
  }

#pragma unroll
  for (int r = 0; r < 4; ++r) {
    float inv = 1.0f / lf[r];
    int q = qt * 64 + wid * 16 + lhi * 4 + r;
#pragma unroll
    for (int nd = 0; nd < 4; ++nd)
      yb[(size_t)(b * T + q) * 1024 + h * 64 + nd * 16 + l15] = f2bf(o[nd][r] * inv);
  }
}

// ---------------- launcher ----------------
extern "C" void kernel_launch(void* const* d_in, const int* in_sizes, int n_in,
                              void* d_out, int out_size, void* d_ws, size_t ws_size,
                              hipStream_t stream) {
  const float* x = (const float*)d_in[0];     // [2,2048,1024]
  const float* Wa = (const float*)d_in[1];    // [1024,3072]
  const float* Wp = (const float*)d_in[2];    // [1024,1024]
  float* out = (float*)d_out;                 // [2,2048,1024] f32

  char* ws = (char*)d_ws;
  unsigned short* xb  = (unsigned short*)(ws);                       // 8 MB  [4096][1024]
  unsigned short* WaT = (unsigned short*)(ws + (size_t)(8u  << 20)); // 6 MB  [3072][1024]
  unsigned short* WpT = (unsigned short*)(ws + (size_t)(14u << 20)); // 2 MB  [1024][1024]
  unsigned short* qk  = (unsigned short*)(ws + (size_t)(16u << 20)); // 16 MB [4096][2048]
  unsigned short* VT  = (unsigned short*)(ws + (size_t)(32u << 20)); // 8 MB  [32][64][2048]
  unsigned short* yb  = (unsigned short*)(ws + (size_t)(40u << 20)); // 8 MB  [4096][1024]

  prep_kernel<<<dim3(3072), 256, 0, stream>>>(x, xb, Wa, WaT, Wp, WpT);
  gemm_qkv_kernel<<<dim3(1536), 256, 0, stream>>>(xb, WaT, qk, VT);
  attn_kernel<<<dim3(1024), 256, 0, stream>>>(qk, VT, yb);
  gemm_bt64x64_kernel<<<dim3(1024), 256, 0, stream>>>(yb, WpT, out, 4096, 1024, 1024);
}

// Round 21
// 97.558 us; speedup vs baseline: 1.0901x; 1.0901x over previous
//
#include <hip/hip_runtime.h>
#include <hip/hip_bf16.h>
#include <cstdint>
#include <cstddef>
#include <cmath>

typedef __attribute__((ext_vector_type(8))) short short8v;
typedef __attribute__((ext_vector_type(4))) float f32x4;
typedef __attribute__((ext_vector_type(4))) unsigned short ushort4v;

__device__ __forceinline__ unsigned short f2bf(float f) {
  union { float f; uint32_t u; } v; v.f = f;
  uint32_t u = v.u;
  return (unsigned short)((u + 0x7fffu + ((u >> 16) & 1u)) >> 16);
}

__device__ __forceinline__ float bf2f(unsigned short u) {
  union { uint32_t u; float f; } v; v.u = ((uint32_t)u) << 16; return v.f;
}

__device__ __forceinline__ uint32_t pack2bf(float a, float b) {
  __hip_bfloat162 h = __float22bfloat162_rn(make_float2(a, b));
  union { __hip_bfloat162 h; uint32_t u; } c; c.h = h; return c.u;
}

__device__ __forceinline__ void load_lds_16B(const void* g, void* l) {
  __builtin_amdgcn_global_load_lds((const __attribute__((address_space(1))) void*)g,
                                   (__attribute__((address_space(3))) void*)l, 16, 0, 0);
}

// ---------------- fused prep: cvt x -> bf16  +  transpose Wa, Wp ----------------
__global__ __launch_bounds__(256) void prep_kernel(const float* __restrict__ x,
                                                   unsigned short* __restrict__ xb,
                                                   const float* __restrict__ Wa,
                                                   unsigned short* __restrict__ WaT,
                                                   const float* __restrict__ Wp,
                                                   unsigned short* __restrict__ WpT) {
  __shared__ float tile[64][65];
  int bid = blockIdx.x;
  int tid = threadIdx.x;

  if (bid < 2048) {
    int i = bid * 256 + tid;
    const float4* s4 = (const float4*)x + (size_t)i * 2;
    float4 f0 = s4[0], f1 = s4[1];
    short8v o;
    o[0] = (short)f2bf(f0.x); o[1] = (short)f2bf(f0.y);
    o[2] = (short)f2bf(f0.z); o[3] = (short)f2bf(f0.w);
    o[4] = (short)f2bf(f1.x); o[5] = (short)f2bf(f1.y);
    o[6] = (short)f2bf(f1.z); o[7] = (short)f2bf(f1.w);
    *(short8v*)(xb + (size_t)i * 8) = o;
    return;
  }

  int t = bid - 2048;
  const float* W; unsigned short* WT; int N, n0, k0;
  if (t < 768) { W = Wa; WT = WaT; N = 3072; n0 = (t % 48) * 64; k0 = (t / 48) * 64; }
  else { t -= 768; W = Wp; WT = WpT; N = 1024; n0 = (t % 16) * 64; k0 = (t / 16) * 64; }
  const int K = 1024;

#pragma unroll
  for (int i = 0; i < 4; ++i) {
    int idx = i * 256 + tid;
    int r = idx >> 4, c4 = (idx & 15) * 4;
    float4 v = *(const float4*)(W + (size_t)(k0 + r) * N + n0 + c4);
    tile[r][c4] = v.x; tile[r][c4 + 1] = v.y; tile[r][c4 + 2] = v.z; tile[r][c4 + 3] = v.w;
  }
  __syncthreads();
#pragma unroll
  for (int i = 0; i < 4; ++i) {
    int idx = i * 256 + tid;
    int nr = idx >> 4, k4 = (idx & 15) * 4;
    ushort4 o;
    o.x = f2bf(tile[k4 + 0][nr]);
    o.y = f2bf(tile[k4 + 1][nr]);
    o.z = f2bf(tile[k4 + 2][nr]);
    o.w = f2bf(tile[k4 + 3][nr]);
    *(ushort4*)(WT + (size_t)(n0 + nr) * K + k0 + k4) = o;
  }
}

// ---------------- GEMM1: qkv projection 128x128 (grid 768), fused V transpose --------
__global__ __launch_bounds__(256) void gemm_qkv_kernel(const unsigned short* __restrict__ A,
                                                       const unsigned short* __restrict__ BT,
                                                       unsigned short* __restrict__ qk,
                                                       unsigned short* __restrict__ VT) {
  const int K = 1024, N = 3072;
  __shared__ __align__(16) char lds[32768];
  char* As = lds;
  char* Bs = lds + 16384;

  int nbn = N >> 7;
  int nwg = gridDim.x;
  int wg = blockIdx.x;
  int per = nwg >> 3;
  int swz = (wg & 7) * per + (wg >> 3);
  int tm = swz / nbn, tn = swz % nbn;

  int tid = threadIdx.x;
  int wid = tid >> 6, lane = tid & 63;
  int l15 = lane & 15, lhi = lane >> 4;
  int wm = wid >> 1, wn = wid & 1;

  const unsigned short* Abase = A + (size_t)(tm * 128) * K;
  const unsigned short* Bbase = BT + (size_t)(tn * 128) * K;

  size_t ofs[4];
#pragma unroll
  for (int i = 0; i < 4; ++i) {
    int row = i * 32 + (tid >> 3);
    int ss = (tid & 7) ^ (row & 7);
    ofs[i] = (size_t)row * K + ss * 8;
  }

  f32x4 acc[4][4] = {};

  for (int kt = 0; kt < K; kt += 64) {
    __syncthreads();
#pragma unroll
    for (int i = 0; i < 4; ++i)
      load_lds_16B(Abase + ofs[i] + kt, As + i * 4096 + tid * 16);
#pragma unroll
    for (int i = 0; i < 4; ++i)
      load_lds_16B(Bbase + ofs[i] + kt, Bs + i * 4096 + tid * 16);
    __syncthreads();

#pragma unroll
    for (int ks = 0; ks < 2; ++ks) {
      short8v af[4], bfr[4];
#pragma unroll
      for (int mi = 0; mi < 4; ++mi) {
        int row = wm * 64 + mi * 16 + l15;
        int ss = (ks * 4 + lhi) ^ (row & 7);
        af[mi] = *(const short8v*)(As + row * 128 + ss * 16);
      }
#pragma unroll
      for (int ni = 0; ni < 4; ++ni) {
        int row = wn * 64 + ni * 16 + l15;
        int ss = (ks * 4 + lhi) ^ (row & 7);
        bfr[ni] = *(const short8v*)(Bs + row * 128 + ss * 16);
      }
#pragma unroll
      for (int mi = 0; mi < 4; ++mi)
#pragma unroll
        for (int ni = 0; ni < 4; ++ni)
          acc[mi][ni] = __builtin_amdgcn_mfma_f32_16x16x32_bf16(af[mi], bfr[ni], acc[mi][ni], 0, 0, 0);
    }
  }

#pragma unroll
  for (int mi = 0; mi < 4; ++mi)
#pragma unroll
    for (int ni = 0; ni < 4; ++ni) {
      int col = tn * 128 + wn * 64 + ni * 16 + l15;
      int row0 = tm * 128 + wm * 64 + mi * 16 + lhi * 4;
      if (col < 2048) {
#pragma unroll
        for (int r = 0; r < 4; ++r)
          qk[(size_t)(row0 + r) * 2048 + col] = f2bf(acc[mi][ni][r]);
      } else {
        int hl = col - 2048, hh = hl >> 6, d = hl & 63;
        int bb = row0 >> 11, tl = row0 & 2047;
        int tc = tl >> 6, k = (tl & 63) >> 2;
        int c4 = ((k >> 3) << 5) | ((k & 3) << 3) | (k & 4);
        ushort4 w;
        w.x = f2bf(acc[mi][ni][0]); w.y = f2bf(acc[mi][ni][1]);
        w.z = f2bf(acc[mi][ni][2]); w.w = f2bf(acc[mi][ni][3]);
        *(ushort4*)(VT + ((size_t)((bb * 16 + hh) * 64 + d)) * 2048 + tc * 64 + c4) = w;
      }
    }
}

// ---------------- GEMM2: 64x64 tiles (f32 out), grid 1024 = 4 blocks/CU ----------------
__global__ __launch_bounds__(256) void gemm_bt64x64_kernel(const unsigned short* __restrict__ A,
                                                           const unsigned short* __restrict__ BT,
                                                           float* __restrict__ Cout,
                                                           int M, int N, int K) {
  __shared__ __align__(16) char lds[16384];
  char* As = lds;
  char* Bs = lds + 8192;

  int nbn = N >> 6;
  int nwg = gridDim.x;
  int wg = blockIdx.x;
  int per = nwg >> 3;
  int swz = (wg & 7) * per + (wg >> 3);
  int tm = swz / nbn, tn = swz % nbn;

  int tid = threadIdx.x;
  int wid = tid >> 6, lane = tid & 63;
  int l15 = lane & 15, lhi = lane >> 4;
  int wm = wid >> 1, wn = wid & 1;

  const unsigned short* Abase = A + (size_t)(tm * 64) * K;
  const unsigned short* Bbase = BT + (size_t)(tn * 64) * K;

  size_t ofs2[2];
#pragma unroll
  for (int i = 0; i < 2; ++i) {
    int row = i * 32 + (tid >> 3);
    int ss = (tid & 7) ^ (row & 7);
    ofs2[i] = (size_t)row * K + ss * 8;
  }

  f32x4 acc[2][2] = {};

  for (int kt = 0; kt < K; kt += 64) {
    __syncthreads();
#pragma unroll
    for (int i = 0; i < 2; ++i)
      load_lds_16B(Abase + ofs2[i] + kt, As + i * 4096 + tid * 16);
#pragma unroll
    for (int i = 0; i < 2; ++i)
      load_lds_16B(Bbase + ofs2[i] + kt, Bs + i * 4096 + tid * 16);
    __syncthreads();

#pragma unroll
    for (int ks = 0; ks < 2; ++ks) {
      short8v af[2], bfr[2];
#pragma unroll
      for (int mi = 0; mi < 2; ++mi) {
        int row = wm * 32 + mi * 16 + l15;
        int ss = (ks * 4 + lhi) ^ (row & 7);
        af[mi] = *(const short8v*)(As + row * 128 + ss * 16);
      }
#pragma unroll
      for (int ni = 0; ni < 2; ++ni) {
        int row = wn * 32 + ni * 16 + l15;
        int ss = (ks * 4 + lhi) ^ (row & 7);
        bfr[ni] = *(const short8v*)(Bs + row * 128 + ss * 16);
      }
#pragma unroll
      for (int mi = 0; mi < 2; ++mi)
#pragma unroll
        for (int ni = 0; ni < 2; ++ni)
          acc[mi][ni] = __builtin_amdgcn_mfma_f32_16x16x32_bf16(af[mi], bfr[ni], acc[mi][ni], 0, 0, 0);
    }
  }

#pragma unroll
  for (int mi = 0; mi < 2; ++mi)
#pragma unroll
    for (int ni = 0; ni < 2; ++ni)
#pragma unroll
      for (int r = 0; r < 4; ++r) {
        int row = tm * 64 + wm * 32 + mi * 16 + lhi * 4 + r;
        int col = tn * 64 + wn * 32 + ni * 16 + l15;
        Cout[(size_t)row * N + col] = acc[mi][ni][r];
      }
}

// ---------------- causal flash attention (r17/r19 version, proven 43 us) ----------------
__device__ __forceinline__ short8v scale_q(short8v q) {
  short8v r;
#pragma unroll
  for (int j = 0; j < 8; ++j)
    r[j] = (short)f2bf(bf2f((unsigned short)q[j]) * 0.18033688f);  // 0.125*log2(e)
  return r;
}

__device__ __forceinline__ void mask_diag(f32x4 s[4], int q_abs, int k0, int lhi) {
#pragma unroll
  for (int ni = 0; ni < 4; ++ni)
#pragma unroll
    for (int r = 0; r < 4; ++r) {
      int kv = k0 + ni * 16 + lhi * 4 + r;
      if (kv > q_abs) s[ni][r] = -1e30f;
    }
}

__device__ __forceinline__ void exp_p(f32x4 s[4]) {
#pragma unroll
  for (int ni = 0; ni < 4; ++ni)
#pragma unroll
    for (int r = 0; r < 4; ++r)
      s[ni][r] = exp2f(s[ni][r]);
}

// pa[ks] elems (jj = t*4+u): P[q=l15][kv = ks*32 + t*16 + lhi*4 + u] = s[ks*2+t][u]
__device__ __forceinline__ void repack_pa(const f32x4 s[4], short8v pa[2]) {
#pragma unroll
  for (int ks = 0; ks < 2; ++ks) {
    union { uint32_t u[4]; short8v v; } pk;
    pk.u[0] = pack2bf(s[2 * ks][0], s[2 * ks][1]);
    pk.u[1] = pack2bf(s[2 * ks][2], s[2 * ks][3]);
    pk.u[2] = pack2bf(s[2 * ks + 1][0], s[2 * ks + 1][1]);
    pk.u[3] = pack2bf(s[2 * ks + 1][2], s[2 * ks + 1][3]);
    pa[ks] = pk.v;
  }
}

__global__ __launch_bounds__(256) void attn_kernel(const unsigned short* __restrict__ qk,
                                                   const unsigned short* __restrict__ VT,
                                                   unsigned short* __restrict__ yb) {
  const int T = 2048, LD = 2048;
  int bid = blockIdx.x;                 // 1024 blocks
  int qt = 31 - (bid >> 5);             // LPT: biggest tiles dispatch first
  int bh = bid & 31;                    // bid%8 == bh%8 -> per-head XCD affinity
  int b = bh >> 4, h = bh & 15;

  int tid = threadIdx.x;
  int wid = tid >> 6, lane = tid & 63;
  int l15 = lane & 15, lhi = lane >> 4;

  __shared__ __align__(16) char Ks[2][8192];   // [64 kv][64 d] bf16, slot^=(kv&7)
  __shared__ __align__(16) char Vt[2][8192];   // [64 d][64 c] bf16, slot^=(d&7)

  union { uint32_t u[4]; short8v v; } ob;
  ob.u[0] = ob.u[1] = ob.u[2] = ob.u[3] = 0x3F803F80u;
  const short8v onesv = ob.v;

  int qrow = qt * 64 + wid * 16 + l15;
  const unsigned short* qp = qk + (size_t)(b * T + qrow) * LD + h * 64;
  short8v qf[2];
  qf[0] = scale_q(*(const short8v*)(qp + lhi * 8));
  qf[1] = scale_q(*(const short8v*)(qp + 32 + lhi * 8));

  const unsigned short* kbase = qk + (size_t)b * T * LD + 1024 + h * 64;
  const unsigned short* vtbase = VT + (size_t)(b * 16 + h) * 64 * 2048;

  f32x4 o[4] = {};
  f32x4 lf = {};
  int q_abs = qrow;
  int nt = qt + 1;

  auto stageK = [&](int s) {
#pragma unroll
    for (int i2 = 0; i2 < 2; ++i2) {
      int row = i2 * 32 + (tid >> 3);
      int ss = (tid & 7) ^ (row & 7);
      load_lds_16B(kbase + (size_t)(s * 64 + row) * LD + ss * 8, Ks[s & 1] + i2 * 4096 + tid * 16);
    }
  };
  auto stageV = [&](int s) {
#pragma unroll
    for (int i2 = 0; i2 < 2; ++i2) {
      int row = i2 * 32 + (tid >> 3);
      int ss = (tid & 7) ^ (row & 7);
      load_lds_16B(vtbase + (size_t)row * 2048 + s * 64 + ss * 8, Vt[s & 1] + i2 * 4096 + tid * 16);
    }
  };

  stageK(0); stageV(0);
  __syncthreads();

  for (int s = 0; s < nt; ++s) {
    if (s + 1 < nt) { stageK(s + 1); stageV(s + 1); }

    const char* KC = Ks[s & 1];
    const char* VC = Vt[s & 1];
    int k0 = s * 64;

    f32x4 sv[4] = {};
    __builtin_amdgcn_s_setprio(1);
#pragma unroll
    for (int ks = 0; ks < 2; ++ks)
#pragma unroll
      for (int ni = 0; ni < 4; ++ni) {
        int row = ni * 16 + l15;
        int sl = (ks * 4 + lhi) ^ (row & 7);
        short8v kf = *(const short8v*)(KC + row * 128 + sl * 16);
        sv[ni] = __builtin_amdgcn_mfma_f32_16x16x32_bf16(kf, qf[ks], sv[ni], 0, 0, 0);
      }
    __builtin_amdgcn_s_setprio(0);

    if (s == qt) mask_diag(sv, q_abs, k0, lhi);
    exp_p(sv);

    short8v pa[2];
    repack_pa(sv, pa);

    __builtin_amdgcn_s_setprio(1);
#pragma unroll
    for (int ks = 0; ks < 2; ++ks) {
#pragma unroll
      for (int nd = 0; nd < 4; ++nd) {
        int d = nd * 16 + l15;
        int slv = (ks * 4 + lhi) ^ (d & 7);
        short8v bv = *(const short8v*)(VC + d * 128 + slv * 16);
        o[nd] = __builtin_amdgcn_mfma_f32_16x16x32_bf16(pa[ks], bv, o[nd], 0, 0, 0);
      }
      lf = __builtin_amdgcn_mfma_f32_16x16x32_bf16(pa[ks], onesv, lf, 0, 0, 0);
    }
    __builtin_amdgcn_s_setprio(0);

    __syncthreads();
  }

#pragma unroll
  for (int r = 0; r < 4; ++r) {
    float inv = 1.0f / lf[r];
    int q = qt * 64 + wid * 16 + lhi * 4 + r;
#pragma unroll
    for (int nd = 0; nd < 4; ++nd)
      yb[(size_t)(b * T + q) * 1024 + h * 64 + nd * 16 + l15] = f2bf(o[nd][r] * inv);
  }
}

// ---------------- launcher ----------------
extern "C" void kernel_launch(void* const* d_in, const int* in_sizes, int n_in,
                              void* d_out, int out_size, void* d_ws, size_t ws_size,
                              hipStream_t stream) {
  const float* x = (const float*)d_in[0];     // [2,2048,1024]
  const float* Wa = (const float*)d_in[1];    // [1024,3072]
  const float* Wp = (const float*)d_in[2];    // [1024,1024]
  float* out = (float*)d_out;                 // [2,2048,1024] f32

  char* ws = (char*)d_ws;
  unsigned short* xb  = (unsigned short*)(ws);                       // 8 MB  [4096][1024]
  unsigned short* WaT = (unsigned short*)(ws + (size_t)(8u  << 20)); // 6 MB  [3072][1024]
  unsigned short* WpT = (unsigned short*)(ws + (size_t)(14u << 20)); // 2 MB  [1024][1024]
  unsigned short* qk  = (unsigned short*)(ws + (size_t)(16u << 20)); // 16 MB [4096][2048]
  unsigned short* VT  = (unsigned short*)(ws + (size_t)(32u << 20)); // 8 MB  [32][64][2048]
  unsigned short* yb  = (unsigned short*)(ws + (size_t)(40u << 20)); // 8 MB  [4096][1024]

  prep_kernel<<<dim3(3072), 256, 0, stream>>>(x, xb, Wa, WaT, Wp, WpT);
  gemm_qkv_kernel<<<dim3(768), 256, 0, stream>>>(xb, WaT, qk, VT);
  attn_kernel<<<dim3(1024), 256, 0, stream>>>(qk, VT, yb);
  gemm_bt64x64_kernel<<<dim3(1024), 256, 0, stream>>>(yb, WpT, out, 4096, 1024, 1024);
}